// Round 18
// baseline (258.942 us; speedup 1.0000x reference)
//
#include <hip/hip_runtime.h>

// RbfNet on MI355X — round 18: layer0_gemm re-parallelized.
// r17's fused kernel collapsed to 1875 x 4-wave blocks with 4 serial nodes/wave
// (occupancy 34%, 51us). Now: 1024-thread blocks (16 waves), wave w owns node w for
// the gather/output phase (full TLP, like r16's layer0), then all 16 waves run the
// 16x576 MFMA tile (col-tiles t = w, w+16, w+32<36). Same math, same outputs.
// Structure: UL[j] = [x_j @ cW (p-major, 512) | x_j @ fW (64)]; conv(x)[i] =
// sum_e w0*U[j,p] + w1*U[j,p+1]; layer3 via T[j][p] = ansc2[j] @ cW3[p] (fused in conv2).
// Edge record (4B): j(15b) | p(3b) | round(w0*16383)(14b); w1 = 1-w0. Self-edges dropped.

#define CAP 48

typedef __attribute__((ext_vector_type(8))) short short8;
typedef __attribute__((ext_vector_type(4))) short short4v;
typedef __attribute__((ext_vector_type(4))) float f32x4;

__device__ __forceinline__ short bf16s(float f) {   // fp32 -> bf16 RNE
  unsigned u = __float_as_uint(f);
  return (short)((u + 0x7FFF + ((u >> 16) & 1)) >> 16);
}
__device__ __forceinline__ float b2f(unsigned short s) {
  return __uint_as_float(((unsigned)s) << 16);
}

// ---------- fused: edge-bucket build (blocks < fillBlocks) + WTul prep (rest) ----------
__global__ void fill_prep(const float* __restrict__ dist,
                          const int* __restrict__ fi, const int* __restrict__ fj,
                          int* __restrict__ cnt, int* __restrict__ jw, int nE,
                          const float* __restrict__ cW1, const float* __restrict__ fW1,
                          const float* __restrict__ cW2, const float* __restrict__ fW2,
                          short* __restrict__ wt1, short* __restrict__ wt2,
                          int fillBlocks) {
  if ((int)blockIdx.x < fillBlocks) {
    int e = blockIdx.x * blockDim.x + threadIdx.x;
    if (e >= nE) return;
    int i = fi[e], j = fj[e];
    if (i == j) return;                  // centerIgnore
    float d = fminf(1.0f, fmaxf(-1.0f, dist[e]));
    float u = (d + 1.0f) * 3.5f;         // hat centers: spacing 2/7
    int p = min((int)u, 6);
    float w0 = 1.0f - (u - (float)p);
    int wq = (int)(w0 * 16383.0f + 0.5f);
    int pos = atomicAdd(&cnt[i], 1);
    if (pos < CAP)
      jw[(size_t)i * CAP + pos] = j | (p << 15) | (wq << 18);
  } else {
    int idx = ((int)blockIdx.x - fillBlocks) * blockDim.x + threadIdx.x;
    if (idx >= 2 * 576 * 64) return;
    int sel = idx / (576 * 64);
    int r = idx - sel * (576 * 64);
    int col = r >> 6, ch = r & 63;
    const float* cW = sel ? cW2 : cW1;
    const float* fW = sel ? fW2 : fW1;
    float v;
    if (col < 512) {
      int p = col >> 6, co = col & 63;
      v = cW[((size_t)p * 64 + ch) * 64 + co];
    } else {
      v = fW[(size_t)ch * 64 + (col - 512)];
    }
    (sel ? wt2 : wt1)[(size_t)col * 64 + ch] = bf16s(v);
  }
}

// ---------- FUSED layer0 + gemm_ul1: 1024 threads, 16 waves, wave-per-node gather ----------
__global__ __launch_bounds__(1024) void layer0_gemm(
    const float* __restrict__ X,      // [n,4] fp32
    const int* __restrict__ cnt, const int* __restrict__ jw,
    const float* __restrict__ cW0,    // [8*4*32]
    const float* __restrict__ cb0,
    const float* __restrict__ fW0,    // [4*32]
    const float* __restrict__ fb0,
    const short* __restrict__ WTul,   // [576,64] bf16 layer-1 weights (L2-resident)
    unsigned short* __restrict__ UL, int n) {
  __shared__ float sW[1024];
  __shared__ float sF[128];
  __shared__ float sB[64];
  __shared__ float sacc[16][32];
  __shared__ __align__(16) unsigned short sXa[16 * 64];   // ansc0 tile, bf16
  __shared__ __align__(16) short sUL[16 * 584];           // UL staging
  const int tid = threadIdx.x;
  const int w = tid >> 6;                 // wave 0..15
  const int lane = tid & 63;
  const int nodeBase = blockIdx.x * 16;
  const int i = nodeBase + w;             // wave w owns node w
  const bool valid = (i < n);

  sW[tid] = cW0[tid];                     // exactly 1024 threads
  if (tid < 128) sF[tid] = fW0[tid];
  else if (tid < 160) sB[tid - 128] = cb0[tid - 128];
  else if (tid < 192) sB[tid - 160 + 32] = fb0[tid - 160];
  if (tid < 512) sacc[tid >> 5][tid & 31] = 0.0f;
  __syncthreads();

  // ---- gather: lane = edge index of node i (wave-parallel, like r16 layer0)
  if (valid && lane < min(cnt[i], CAP)) {
    int v = jw[(size_t)i * CAP + lane];
    int j = v & 0x7FFF;
    int p = (v >> 15) & 7;
    float w0 = (float)((unsigned)v >> 18) * (1.0f / 16383.0f);
    float w1 = 1.0f - w0;
    float4 x = *(const float4*)(X + (size_t)j * 4);
    float* a = sacc[w];
    atomicAdd(&a[p * 4 + 0], w0 * x.x);
    atomicAdd(&a[p * 4 + 1], w0 * x.y);
    atomicAdd(&a[p * 4 + 2], w0 * x.z);
    atomicAdd(&a[p * 4 + 3], w0 * x.w);
    atomicAdd(&a[(p + 1) * 4 + 0], w1 * x.x);
    atomicAdd(&a[(p + 1) * 4 + 1], w1 * x.y);
    atomicAdd(&a[(p + 1) * 4 + 2], w1 * x.z);
    atomicAdd(&a[(p + 1) * 4 + 3], w1 * x.w);
  }
  __syncthreads();

  // ---- output: lane = channel of node i; invalid nodes -> zeros
  float vO = 0.0f;
  if (valid) {
    const float4 xi = *(const float4*)(X + (size_t)i * 4);
    if (lane < 32) {                      // lin -> channels 0..31
      vO = sB[32 + lane];
      vO = fmaf(xi.x, sF[0 * 32 + lane], vO);
      vO = fmaf(xi.y, sF[1 * 32 + lane], vO);
      vO = fmaf(xi.z, sF[2 * 32 + lane], vO);
      vO = fmaf(xi.w, sF[3 * 32 + lane], vO);
    } else {                              // conv -> channels 32..63
      const int cc = lane - 32;
      vO = sB[cc];
      #pragma unroll
      for (int k = 0; k < 32; ++k)
        vO = fmaf(sacc[w][k], sW[k * 32 + cc], vO);
    }
    vO = fmaxf(vO, 0.0f);
  }
  sXa[w * 64 + lane] = (unsigned short)bf16s(vO);
  __syncthreads();

  // ---- gemm tile: UL[16,576] = sXa[16,64] @ WTul^T; wave w does tiles w, w+16, w+32
  const int mrow = lane & 15;
  const int quad = lane >> 4;
  short8 b0 = *(const short8*)(sXa + mrow * 64 + quad * 8);
  short8 b1 = *(const short8*)(sXa + mrow * 64 + quad * 8 + 32);
  for (int t = w; t < 36; t += 16) {
    const short* aBase = WTul + (size_t)(t * 16 + mrow) * 64 + quad * 8;
    short8 a0 = *(const short8*)(aBase);
    short8 a1 = *(const short8*)(aBase + 32);
    f32x4 acc = {0, 0, 0, 0};
    acc = __builtin_amdgcn_mfma_f32_16x16x32_bf16(a0, b0, acc, 0, 0, 0);
    acc = __builtin_amdgcn_mfma_f32_16x16x32_bf16(a1, b1, acc, 0, 0, 0);
    short4v pk;
    #pragma unroll
    for (int reg = 0; reg < 4; ++reg) pk[reg] = bf16s(acc[reg]);
    *(short4v*)(sUL + mrow * 584 + t * 16 + quad * 4) = pk;
  }
  __syncthreads();
  // ---- coalesced store: 1024 threads cover 16 rows x 72 chunks of 16B
  const int r = tid >> 6;                 // row 0..15
  const int c0 = tid & 63;                // chunk base
  if (nodeBase + r < n) {
    unsigned short* dst = UL + (size_t)(nodeBase + r) * 576;
    #pragma unroll
    for (int chunk = c0; chunk < 72; chunk += 64)
      *(short8*)(dst + chunk * 8) = *(const short8*)(sUL + r * 584 + chunk * 8);
  }
}

// ---------- dense MFMA GEMM: UL[n,576] = Xb[n,64] @ WTul^T (layer 2) ----------
__global__ __launch_bounds__(256) void gemm_ul(
    const unsigned short* __restrict__ Xb,  // [n,64] bf16
    const short* __restrict__ WTul,         // [576,64] bf16 (L2-resident)
    unsigned short* __restrict__ UL, int n) {
  __shared__ short sUL[16 * 584];
  const int lane = threadIdx.x & 63;
  const int w = threadIdx.x >> 6;
  const int mrow = lane & 15;
  const int quad = lane >> 4;
  const int nodeBase = blockIdx.x * 16;
  const int bnode = min(nodeBase + mrow, n - 1);
  const unsigned short* bBase = Xb + (size_t)bnode * 64 + quad * 8;
  short8 b0 = *(const short8*)(bBase);
  short8 b1 = *(const short8*)(bBase + 32);
  #pragma unroll
  for (int t = 0; t < 9; ++t) {
    const int ct = w * 9 + t;
    const short* aBase = WTul + (size_t)(ct * 16 + mrow) * 64 + quad * 8;
    short8 a0 = *(const short8*)(aBase);
    short8 a1 = *(const short8*)(aBase + 32);
    f32x4 acc = {0, 0, 0, 0};
    acc = __builtin_amdgcn_mfma_f32_16x16x32_bf16(a0, b0, acc, 0, 0, 0);
    acc = __builtin_amdgcn_mfma_f32_16x16x32_bf16(a1, b1, acc, 0, 0, 0);
    short4v pk;
    #pragma unroll
    for (int reg = 0; reg < 4; ++reg) pk[reg] = bf16s(acc[reg]);
    *(short4v*)(sUL + mrow * 584 + ct * 16 + quad * 4) = pk;
  }
  __syncthreads();
  const int r = threadIdx.x >> 4;
  const int c0 = threadIdx.x & 15;
  if (nodeBase + r < n) {
    unsigned short* dst = UL + (size_t)(nodeBase + r) * 576;
    #pragma unroll
    for (int chunk = c0; chunk < 72; chunk += 16)
      *(short8*)(dst + chunk * 8) = *(const short8*)(sUL + r * 584 + chunk * 8);
  }
}

// ---------- conv gather: wave per node; ONE uint load per edge (256B span = u0|u1) ----------
template <bool HAS_RES, bool STORE_ANS, bool COMPUTE_T>
__global__ __launch_bounds__(256) void conv_gather(
    const unsigned short* __restrict__ UL,  // [n,576] bf16
    const int* __restrict__ cnt, const int* __restrict__ jw,
    const float* __restrict__ cb, const float* __restrict__ fb,
    const float* __restrict__ resid,        // fp32 [n,64] or null
    const float* __restrict__ cW3,          // [8,64,2] (only if COMPUTE_T)
    float* __restrict__ T,                  // [n,16] fp32 (only if COMPUTE_T)
    float* __restrict__ outAns,             // fp32 [n,64] or null
    unsigned short* __restrict__ outAnsc, int n) {  // bf16 [n,64]
  const int lane = threadIdx.x & 63;
  const int half = lane >> 5;               // 0 -> u0 (w0), 1 -> u1 (w1)
  const int pl = lane & 31;                 // channel-pair index
  const int i = (blockIdx.x * blockDim.x + threadIdx.x) >> 6;
  if (i >= n) return;
  int rec = jw[(size_t)i * CAP + (lane < CAP ? lane : 0)];  // lane q holds record q
  const int m = min(cnt[i], CAP);
  const int mc = m - 1;                     // waste-slot clamp target (real record)
  const unsigned short* ULrow = UL + (size_t)i * 576;
  const unsigned Lraw = ((const unsigned*)(ULrow + 512))[pl];
  float rv0 = 0.0f, rv1 = 0.0f;
  if (HAS_RES) {
    float2 rv = *(const float2*)(resid + (size_t)i * 64 + 2 * pl);
    rv0 = rv.x; rv1 = rv.y;
  }
  float accLo = 0.0f, accHi = 0.0f;         // channels 2*pl, 2*pl+1 of this half
  for (int q0 = 0; q0 < m; q0 += 16) {
    unsigned raw[16];
    float w0s[16];
    #pragma unroll
    for (int k = 0; k < 16; ++k) {          // issue all 16 loads before consuming
      int v = __builtin_amdgcn_readlane(rec, min(q0 + k, mc));
      int j = v & 0x7FFF;                   // real record -> in-bounds
      int p = (v >> 15) & 7;
      w0s[k] = (float)((unsigned)v >> 18) * (1.0f / 16383.0f);
      raw[k] = ((const unsigned*)(UL + (size_t)j * 576 + p * 64))[lane];
    }
    #pragma unroll
    for (int k = 0; k < 16; ++k) {
      bool ok = (q0 + k < m);
      float w = half ? (1.0f - w0s[k]) : w0s[k];
      w = ok ? w : 0.0f;
      accLo = fmaf(w, __uint_as_float(raw[k] << 16), accLo);
      accHi = fmaf(w, __uint_as_float(raw[k] & 0xFFFF0000u), accHi);
    }
  }
  accLo += __shfl_xor(accLo, 32, 64);       // merge u0/u1 halves
  accHi += __shfl_xor(accHi, 32, 64);
  if (half == 0) {                          // lanes 0-31 do the epilogue
    const int c0i = 2 * pl, c1i = c0i + 1;
    float L0 = __uint_as_float(Lraw << 16);
    float L1 = __uint_as_float(Lraw & 0xFFFF0000u);
    float o0 = accLo + L0 + cb[c0i] + fb[c0i] + rv0;
    float o1 = accHi + L1 + cb[c1i] + fb[c1i] + rv1;
    if (STORE_ANS)
      *(float2*)(outAns + (size_t)i * 64 + c0i) = make_float2(o0, o1);
    unsigned short xb0 = (unsigned short)bf16s(fmaxf(o0, 0.0f));
    unsigned short xb1 = (unsigned short)bf16s(fmaxf(o1, 0.0f));
    ((unsigned*)(outAnsc + (size_t)i * 64))[pl] = (unsigned)xb0 | ((unsigned)xb1 << 16);
    if (COMPUTE_T) {
      float x0 = b2f(xb0), x1 = b2f(xb1);
      float c[16];
      #pragma unroll
      for (int t = 0; t < 16; ++t) {
        const float* wrow = cW3 + ((size_t)(t >> 1) * 64) * 2 + (t & 1);
        c[t] = x0 * wrow[c0i * 2] + x1 * wrow[c1i * 2];
      }
      #pragma unroll
      for (int off = 16; off > 0; off >>= 1) {   // butterfly within lanes 0-31
        #pragma unroll
        for (int t = 0; t < 16; ++t) c[t] += __shfl_xor(c[t], off, 64);
      }
      if (pl == 0) {
        float* tr = T + (size_t)i * 16;
        #pragma unroll
        for (int t = 0; t < 16; ++t) tr[t] = c[t];
      }
    }
  }
}

// ---------- layer 3: wave per node, lane = edge; 16B/edge from T; + lin; reduce ----------
__global__ __launch_bounds__(256, 4) void layer3_kernel(
    const unsigned short* __restrict__ Xb,  // ansc2 [n,64] bf16
    const float* __restrict__ T,            // [n,16] fp32
    const int* __restrict__ cnt, const int* __restrict__ jw,
    const float* __restrict__ cb3, const float* __restrict__ fb3,
    const float* __restrict__ fW3,          // [64,2]
    float* __restrict__ out, int n) {
  const int lane = threadIdx.x & 63;
  const int i = (blockIdx.x * blockDim.x + threadIdx.x) >> 6;
  if (i >= n) return;
  const int m = min(cnt[i], CAP);
  float c0 = 0.0f, c1 = 0.0f;
  if (lane < m) {                      // lane = edge index (fully lane-parallel)
    int v = jw[(size_t)i * CAP + lane];
    int j = min(v & 0x7FFF, n - 1);
    int p = (v >> 15) & 7;
    float w0 = (float)((unsigned)v >> 18) * (1.0f / 16383.0f);
    float w1 = 1.0f - w0;
    const float* tb = T + (size_t)j * 16 + p * 2;
    float2 ta = *(const float2*)(tb);
    float2 tc = *(const float2*)(tb + 2);
    c0 = w0 * ta.x + w1 * tc.x;
    c1 = w0 * ta.y + w1 * tc.y;
  }
  // linear path: lane = channel
  float xi = b2f(Xb[(size_t)i * 64 + lane]);
  float2 fw = *(const float2*)(fW3 + lane * 2);
  c0 = fmaf(xi, fw.x, c0);
  c1 = fmaf(xi, fw.y, c1);
  #pragma unroll
  for (int off = 32; off > 0; off >>= 1) {
    c0 += __shfl_xor(c0, off, 64);
    c1 += __shfl_xor(c1, off, 64);
  }
  if (lane == 0) {
    out[(size_t)i * 2 + 0] = c0 + cb3[0] + fb3[0];
    out[(size_t)i * 2 + 1] = c1 + cb3[1] + fb3[1];
  }
}

extern "C" void kernel_launch(void* const* d_in, const int* in_sizes, int n_in,
                              void* d_out, int out_size, void* d_ws, size_t ws_size,
                              hipStream_t stream) {
  const float* X    = (const float*)d_in[0];
  const int*   fi   = (const int*)d_in[1];
  const int*   fj   = (const int*)d_in[2];
  const float* dist = (const float*)d_in[3];
  const float* cW0 = (const float*)d_in[4];  const float* cb0 = (const float*)d_in[5];
  const float* fW0 = (const float*)d_in[6];  const float* fb0 = (const float*)d_in[7];
  const float* cW1 = (const float*)d_in[8];  const float* cb1 = (const float*)d_in[9];
  const float* fW1 = (const float*)d_in[10]; const float* fb1 = (const float*)d_in[11];
  const float* cW2 = (const float*)d_in[12]; const float* cb2 = (const float*)d_in[13];
  const float* fW2 = (const float*)d_in[14]; const float* fb2 = (const float*)d_in[15];
  const float* cW3 = (const float*)d_in[16]; const float* cb3 = (const float*)d_in[17];
  const float* fW3 = (const float*)d_in[18]; const float* fb3 = (const float*)d_in[19];
  float* out = (float*)d_out;

  const int n  = in_sizes[0] / 4;  // N = 30000
  const int nE = in_sizes[1];      // E = 480000

  // workspace (~58 MB): UL bf16[n*576] | ansc2 bf16[n*64] | ansc1 bf16[n*64]
  //   | ans1 fp32[n*64] | T fp32[n*16] | wtul1[576*64] | wtul2 | jw[n*CAP] | cnt[n]
  unsigned short* UL    = (unsigned short*)d_ws;
  unsigned short* ansc2 = UL + (size_t)n * 576;     // conv2 output (layer3 input)
  unsigned short* ansc1 = ansc2 + (size_t)n * 64;
  float*          ans1  = (float*)(ansc1 + (size_t)n * 64);
  float* T     = ans1 + (size_t)n * 64;
  short* wtul1 = (short*)(T + (size_t)n * 16);
  short* wtul2 = wtul1 + 576 * 64;
  int*   jw    = (int*)(wtul2 + 576 * 64);
  int*   cnt   = jw + (size_t)n * CAP;

  hipMemsetAsync(cnt, 0, (size_t)n * sizeof(int), stream);
  const int fillBlocks = (nE + 255) / 256;
  const int prepBlocks = (2 * 576 * 64 + 255) / 256;
  fill_prep<<<fillBlocks + prepBlocks, 256, 0, stream>>>(
      dist, fi, fj, cnt, jw, nE, cW1, fW1, cW2, fW2, wtul1, wtul2, fillBlocks);

  // layer 0 + gemm_ul layer 1 (fused; 1024-thread blocks, wave-per-node gather)
  layer0_gemm<<<(n + 15) / 16, 1024, 0, stream>>>(X, cnt, jw, cW0, cb0, fW0, fb0,
                                                  wtul1, UL, n);
  // layer 1 conv
  conv_gather<false, true, false><<<(n * 64 + 255) / 256, 256, 0, stream>>>(
      UL, cnt, jw, cb1, fb1, nullptr, nullptr, nullptr, ans1, ansc1, n);
  // layer 2
  gemm_ul<<<(n + 15) / 16, 256, 0, stream>>>(ansc1, wtul2, UL, n);
  conv_gather<true, false, true><<<(n * 64 + 255) / 256, 256, 0, stream>>>(
      UL, cnt, jw, cb2, fb2, ans1, cW3, T, nullptr, ansc2, n);
  // layer 3
  layer3_kernel<<<(n * 64 + 255) / 256, 256, 0, stream>>>(ansc2, T, cnt, jw,
                                                          cb3, fb3, fW3, out, n);
}